// Round 1
// baseline (168.365 us; speedup 1.0000x reference)
//
#include <hip/hip_runtime.h>
#include <hip/hip_bf16.h>

// Problem constants (fixed by the reference)
#define Bb 4
#define Tt 2048
#define Dd 256
#define Hh 8
#define HDd 32
#define Mm (Bb * Tt)   // 8192

typedef __attribute__((ext_vector_type(8))) short short8v;  // 8 x bf16 (4 VGPR) MFMA A/B frag
typedef __attribute__((ext_vector_type(4))) short short4v;
typedef __attribute__((ext_vector_type(4))) float f32x4;    // MFMA C/D frag

#define MFMA16(a, b, c) __builtin_amdgcn_mfma_f32_16x16x32_bf16(a, b, c, 0, 0, 0)

// f32 -> bf16 round-to-nearest-even (finite inputs only; 3 VALU ops)
__device__ __forceinline__ short f2bf(float f) {
  union { float f; unsigned u; } x; x.f = f;
  unsigned r = x.u + 0x7fffu + ((x.u >> 16) & 1u);
  return (short)(r >> 16);
}

// ---------------------------------------------------------------------------
// Kernel 1: fused 5-way projection GEMM.  Y_p = X_p @ W_p^T  (bf16 out)
//   p = 0..4 -> {content@Wqc, content@Wkc, content@Wv, category@Wqk, category@Wkk}
// 128x128 tile, BK=32, 4 waves (2x2), each wave 64x64 via 4x4 16x16x32 MFMA.
// f32 global -> bf16 LDS conversion fused into staging. Rows padded to 40
// elements (80B) so frag ds_read_b128 is ~2-way conflict instead of 8-way.
// ---------------------------------------------------------------------------
__global__ __launch_bounds__(256)
void proj_kernel(const float* __restrict__ content, const float* __restrict__ category,
                 const float* __restrict__ Wqc, const float* __restrict__ Wkc,
                 const float* __restrict__ Wv, const float* __restrict__ Wqk,
                 const float* __restrict__ Wkk, short* __restrict__ ws) {
  __shared__ short Al[128][40];
  __shared__ short Bl[128][40];

  const int mt = blockIdx.x;            // 0..63
  const int nt = blockIdx.y;            // 0..9
  const int p  = nt >> 1;               // projection index
  const int n0 = (nt & 1) << 7;         // 0 or 128

  const float* X = (p < 3) ? content : category;
  const float* W = (p == 0) ? Wqc : (p == 1) ? Wkc : (p == 2) ? Wv : (p == 3) ? Wqk : Wkk;
  short* Y = ws + (size_t)p * ((size_t)Mm * Dd);

  const int tid  = threadIdx.x;
  const int lane = tid & 63;
  const int wv   = tid >> 6;
  const int wm   = (wv >> 1) << 6;      // wave row offset (0/64)
  const int wn   = (wv & 1) << 6;       // wave col offset (0/64)
  const int l15  = lane & 15;
  const int l4   = lane >> 4;

  const f32x4 zero = {0.f, 0.f, 0.f, 0.f};
  f32x4 acc[4][4];
#pragma unroll
  for (int i = 0; i < 4; i++)
#pragma unroll
    for (int j = 0; j < 4; j++) acc[i][j] = zero;

  const int rs = tid >> 3;              // 0..31
  const int cs = (tid & 7) << 2;        // 0..28 (f32 elems)

  for (int k0 = 0; k0 < Dd; k0 += 32) {
    // stage A (X tile) and B (W tile), converting f32 -> bf16
#pragma unroll
    for (int pass = 0; pass < 4; pass++) {
      const int r = rs + (pass << 5);
      const float4 va = *reinterpret_cast<const float4*>(&X[(size_t)(mt * 128 + r) * Dd + k0 + cs]);
      short4v sa; sa[0] = f2bf(va.x); sa[1] = f2bf(va.y); sa[2] = f2bf(va.z); sa[3] = f2bf(va.w);
      *reinterpret_cast<short4v*>(&Al[r][cs]) = sa;
      const float4 vb = *reinterpret_cast<const float4*>(&W[(size_t)(n0 + r) * Dd + k0 + cs]);
      short4v sb; sb[0] = f2bf(vb.x); sb[1] = f2bf(vb.y); sb[2] = f2bf(vb.z); sb[3] = f2bf(vb.w);
      *reinterpret_cast<short4v*>(&Bl[r][cs]) = sb;
    }
    __syncthreads();

    short8v af[4], bfr[4];
#pragma unroll
    for (int i = 0; i < 4; i++)
      af[i] = *reinterpret_cast<const short8v*>(&Al[wm + i * 16 + l15][l4 * 8]);
#pragma unroll
    for (int j = 0; j < 4; j++)
      bfr[j] = *reinterpret_cast<const short8v*>(&Bl[wn + j * 16 + l15][l4 * 8]);
#pragma unroll
    for (int i = 0; i < 4; i++)
#pragma unroll
      for (int j = 0; j < 4; j++)
        acc[i][j] = MFMA16(af[i], bfr[j], acc[i][j]);
    __syncthreads();
  }

  // epilogue: bf16 scalar stores (C/D layout: row=(l>>4)*4+e, col=l&15)
#pragma unroll
  for (int i = 0; i < 4; i++) {
    const int rb = mt * 128 + wm + i * 16 + (l4 << 2);
#pragma unroll
    for (int j = 0; j < 4; j++) {
      const int c = n0 + wn + j * 16 + l15;
#pragma unroll
      for (int e = 0; e < 4; e++)
        Y[(size_t)(rb + e) * Dd + c] = f2bf(acc[i][j][e]);
    }
  }
}

// ---------------------------------------------------------------------------
// Kernel 2: dual causal flash attention (content + category streams, shared V).
// Grid: (B*H, T/64). Block: 256 threads = 4 waves, wave w owns q-rows w*16..+15.
// HD=32 -> one 16x16x32 MFMA covers the whole K-dim for each S fragment.
// Online softmax per stream; O accumulated separately, combined by alpha at end.
// ---------------------------------------------------------------------------
__global__ __launch_bounds__(256)
void attn_kernel(const short* __restrict__ Qc, const short* __restrict__ Kc,
                 const short* __restrict__ V, const short* __restrict__ Qk,
                 const short* __restrict__ Kk, short* __restrict__ AO,
                 const float* __restrict__ alpha_logit_p) {
  __shared__ short Kcl[64][40];      // K tile (content), padded
  __shared__ short Kkl[64][40];      // K tile (category)
  __shared__ short Vtl[32][72];      // V tile transposed [d][kv], padded
  __shared__ short Pl[4][2][16][72]; // per-wave, per-stream P tile, padded

  const int bh = blockIdx.x;                        // 0..31
  const int qt = (int)gridDim.y - 1 - (int)blockIdx.y; // heavy tiles first
  const int b  = bh >> 3;
  const int h  = bh & 7;
  const size_t rowbase = (size_t)b * Tt;
  const int q0 = qt << 6;

  const int tid  = threadIdx.x;
  const int lane = tid & 63;
  const int wv   = tid >> 6;
  const int l15  = lane & 15;
  const int l4   = lane >> 4;

  // Q fragments straight from global (A-frag: row=l%16, k=(l/16)*8..+7)
  const size_t qrow = rowbase + q0 + wv * 16 + l15;
  const short8v qfc = *reinterpret_cast<const short8v*>(&Qc[qrow * Dd + h * 32 + l4 * 8]);
  const short8v qfk = *reinterpret_cast<const short8v*>(&Qk[qrow * Dd + h * 32 + l4 * 8]);

  const f32x4 zero = {0.f, 0.f, 0.f, 0.f};
  float mx[2][4], ls[2][4];
  f32x4 ov[2][2];
#pragma unroll
  for (int s = 0; s < 2; s++) {
#pragma unroll
    for (int e = 0; e < 4; e++) { mx[s][e] = -1e30f; ls[s][e] = 0.f; }
#pragma unroll
    for (int n = 0; n < 2; n++) ov[s][n] = zero;
  }

  const float c1 = 0.17677669529663689f * 1.4426950408889634f; // scale * log2(e)

  const int rs = tid >> 2;  // 0..63 (staging row)
  const int sg = tid & 3;   // 0..3  (staging 8-elem segment)

  for (int jt = 0; jt <= qt; jt++) {
    const int k0 = jt << 6;
    // ---- stage K tiles (padded rows) and V transposed ----
    {
      const size_t gr = (rowbase + k0 + rs) * Dd + h * 32 + sg * 8;
      *reinterpret_cast<short8v*>(&Kcl[rs][sg * 8]) = *reinterpret_cast<const short8v*>(&Kc[gr]);
      *reinterpret_cast<short8v*>(&Kkl[rs][sg * 8]) = *reinterpret_cast<const short8v*>(&Kk[gr]);
      const short8v v8 = *reinterpret_cast<const short8v*>(&V[gr]);
#pragma unroll
      for (int j = 0; j < 8; j++) Vtl[sg * 8 + j][rs] = v8[j];
    }
    __syncthreads();

    // ---- S = Q K^T for both streams (4 fragments each, one MFMA per frag) ----
    f32x4 sf[2][4];
#pragma unroll
    for (int f = 0; f < 4; f++) {
      const short8v kbc = *reinterpret_cast<const short8v*>(&Kcl[f * 16 + l15][l4 * 8]);
      sf[0][f] = MFMA16(qfc, kbc, zero);
      const short8v kbk = *reinterpret_cast<const short8v*>(&Kkl[f * 16 + l15][l4 * 8]);
      sf[1][f] = MFMA16(qfk, kbk, zero);
    }
    if (jt == qt) {  // diagonal tile: causal mask (col > row blocked)
#pragma unroll
      for (int f = 0; f < 4; f++)
#pragma unroll
        for (int e = 0; e < 4; e++) {
          const int rg = wv * 16 + l4 * 4 + e;
          const int cg = f * 16 + l15;
          if (cg > rg) { sf[0][f][e] = -1e30f; sf[1][f][e] = -1e30f; }
        }
    }

    // ---- online softmax + PV per stream ----
#pragma unroll
    for (int s = 0; s < 2; s++) {
      float fac[4], tsum[4];
#pragma unroll
      for (int e = 0; e < 4; e++) {
        float v = fmaxf(fmaxf(sf[s][0][e], sf[s][1][e]), fmaxf(sf[s][2][e], sf[s][3][e]));
        v = fmaxf(v, __shfl_xor(v, 1));
        v = fmaxf(v, __shfl_xor(v, 2));
        v = fmaxf(v, __shfl_xor(v, 4));
        v = fmaxf(v, __shfl_xor(v, 8));
        const float mn = fmaxf(mx[s][e], v);
        fac[e] = exp2f((mx[s][e] - mn) * c1);
        mx[s][e] = mn;
        tsum[e] = 0.f;
      }
#pragma unroll
      for (int f = 0; f < 4; f++)
#pragma unroll
        for (int e = 0; e < 4; e++) {
          const float pv = exp2f((sf[s][f][e] - mx[s][e]) * c1);
          sf[s][f][e] = pv;
          tsum[e] += pv;
        }
#pragma unroll
      for (int e = 0; e < 4; e++) {
        float sm = tsum[e];
        sm += __shfl_xor(sm, 1);
        sm += __shfl_xor(sm, 2);
        sm += __shfl_xor(sm, 4);
        sm += __shfl_xor(sm, 8);
        ls[s][e] = ls[s][e] * fac[e] + sm;
      }
#pragma unroll
      for (int n = 0; n < 2; n++)
#pragma unroll
        for (int e = 0; e < 4; e++) ov[s][n][e] *= fac[e];

      // P (C/D layout) -> per-wave LDS, then re-read as A-frags
#pragma unroll
      for (int f = 0; f < 4; f++)
#pragma unroll
        for (int e = 0; e < 4; e++)
          Pl[wv][s][l4 * 4 + e][f * 16 + l15] = f2bf(sf[s][f][e]);
#pragma unroll
      for (int half = 0; half < 2; half++) {
        const short8v pa = *reinterpret_cast<const short8v*>(&Pl[wv][s][l15][half * 32 + l4 * 8]);
#pragma unroll
        for (int n = 0; n < 2; n++) {
          const short8v vb = *reinterpret_cast<const short8v*>(&Vtl[n * 16 + l15][half * 32 + l4 * 8]);
          ov[s][n] = MFMA16(pa, vb, ov[s][n]);
        }
      }
    }
    __syncthreads();  // protect K/V LDS before next tile's staging
  }

  // ---- combine streams, normalize, store bf16 ----
  const float al = alpha_logit_p[0];
  const float alpha = 1.f / (1.f + __expf(-al));
#pragma unroll
  for (int n = 0; n < 2; n++)
#pragma unroll
    for (int e = 0; e < 4; e++) {
      const float vout = (1.f - alpha) * ov[0][n][e] / ls[0][e] + alpha * ov[1][n][e] / ls[1][e];
      const size_t r = rowbase + q0 + wv * 16 + l4 * 4 + e;
      AO[r * Dd + h * 32 + n * 16 + l15] = f2bf(vout);
    }
}

// ---------------------------------------------------------------------------
// Kernel 3: output projection  out = AO @ Wo^T + bo  (f32 out)
// ---------------------------------------------------------------------------
__global__ __launch_bounds__(256)
void outproj_kernel(const short* __restrict__ AO, const float* __restrict__ Wo,
                    const float* __restrict__ bo, float* __restrict__ out) {
  __shared__ short Al[128][40];
  __shared__ short Bl[128][40];

  const int mt = blockIdx.x;
  const int n0 = (int)blockIdx.y << 7;

  const int tid  = threadIdx.x;
  const int lane = tid & 63;
  const int wv   = tid >> 6;
  const int wm   = (wv >> 1) << 6;
  const int wn   = (wv & 1) << 6;
  const int l15  = lane & 15;
  const int l4   = lane >> 4;

  const f32x4 zero = {0.f, 0.f, 0.f, 0.f};
  f32x4 acc[4][4];
#pragma unroll
  for (int i = 0; i < 4; i++)
#pragma unroll
    for (int j = 0; j < 4; j++) acc[i][j] = zero;

  const int rs2 = tid >> 2;        // bf16 A staging
  const int sg2 = tid & 3;
  const int rs  = tid >> 3;        // f32 B staging
  const int cs  = (tid & 7) << 2;

  for (int k0 = 0; k0 < Dd; k0 += 32) {
#pragma unroll
    for (int pass = 0; pass < 2; pass++) {
      const int r = rs2 + (pass << 6);
      *reinterpret_cast<short8v*>(&Al[r][sg2 * 8]) =
          *reinterpret_cast<const short8v*>(&AO[(size_t)(mt * 128 + r) * Dd + k0 + sg2 * 8]);
    }
#pragma unroll
    for (int pass = 0; pass < 4; pass++) {
      const int r = rs + (pass << 5);
      const float4 vb = *reinterpret_cast<const float4*>(&Wo[(size_t)(n0 + r) * Dd + k0 + cs]);
      short4v sb; sb[0] = f2bf(vb.x); sb[1] = f2bf(vb.y); sb[2] = f2bf(vb.z); sb[3] = f2bf(vb.w);
      *reinterpret_cast<short4v*>(&Bl[r][cs]) = sb;
    }
    __syncthreads();

    short8v af[4], bfr[4];
#pragma unroll
    for (int i = 0; i < 4; i++)
      af[i] = *reinterpret_cast<const short8v*>(&Al[wm + i * 16 + l15][l4 * 8]);
#pragma unroll
    for (int j = 0; j < 4; j++)
      bfr[j] = *reinterpret_cast<const short8v*>(&Bl[wn + j * 16 + l15][l4 * 8]);
#pragma unroll
    for (int i = 0; i < 4; i++)
#pragma unroll
      for (int j = 0; j < 4; j++)
        acc[i][j] = MFMA16(af[i], bfr[j], acc[i][j]);
    __syncthreads();
  }

#pragma unroll
  for (int i = 0; i < 4; i++) {
    const int rb = mt * 128 + wm + i * 16 + (l4 << 2);
#pragma unroll
    for (int j = 0; j < 4; j++) {
      const int c = n0 + wn + j * 16 + l15;
      const float bias = bo[c];
#pragma unroll
      for (int e = 0; e < 4; e++)
        out[(size_t)(rb + e) * Dd + c] = acc[i][j][e] + bias;
    }
  }
}

// ---------------------------------------------------------------------------
extern "C" void kernel_launch(void* const* d_in, const int* in_sizes, int n_in,
                              void* d_out, int out_size, void* d_ws, size_t ws_size,
                              hipStream_t stream) {
  const float* content = (const float*)d_in[0];
  const float* category = (const float*)d_in[1];
  const float* Wqc = (const float*)d_in[2];
  const float* Wkc = (const float*)d_in[3];
  const float* Wv  = (const float*)d_in[4];
  const float* Wqk = (const float*)d_in[5];
  const float* Wkk = (const float*)d_in[6];
  const float* Wo  = (const float*)d_in[7];
  const float* bo  = (const float*)d_in[8];
  const float* alpha_logit = (const float*)d_in[9];
  float* out = (float*)d_out;

  short* ws = (short*)d_ws;
  const size_t buf = (size_t)Mm * Dd;   // 2M bf16 = 4MB per buffer
  short* Qc = ws + 0 * buf;
  short* Kc = ws + 1 * buf;
  short* V  = ws + 2 * buf;
  short* Qk = ws + 3 * buf;
  short* Kk = ws + 4 * buf;
  short* AO = ws + 5 * buf;             // total 24MB of d_ws

  proj_kernel<<<dim3(64, 10), 256, 0, stream>>>(content, category, Wqc, Wkc, Wv, Wqk, Wkk, ws);
  attn_kernel<<<dim3(32, 32), 256, 0, stream>>>(Qc, Kc, V, Qk, Kk, AO, alpha_logit);
  outproj_kernel<<<dim3(64, 2), 256, 0, stream>>>(AO, Wo, bo, out);
}

// Round 2
// 93.683 us; speedup vs baseline: 1.7972x; 1.7972x over previous
//
#include <hip/hip_runtime.h>
#include <hip/hip_bf16.h>

// Problem constants (fixed by the reference)
#define Bb 4
#define Tt 2048
#define Dd 256
#define Hh 8
#define Mm (Bb * Tt)   // 8192

typedef __attribute__((ext_vector_type(8))) short short8v;   // 8 x bf16
typedef __attribute__((ext_vector_type(4))) short short4v;
typedef __attribute__((ext_vector_type(4))) float f32x4;
typedef __attribute__((ext_vector_type(4))) unsigned uint4v;

#define MFMA16(a, b, c) __builtin_amdgcn_mfma_f32_16x16x32_bf16(a, b, c, 0, 0, 0)

// async global->LDS, 16B per lane; LDS dest is wave-uniform base + lane*16
__device__ __forceinline__ void gload16(const void* g, void* l) {
  __builtin_amdgcn_global_load_lds((const __attribute__((address_space(1))) void*)g,
                                   (__attribute__((address_space(3))) void*)l, 16, 0, 0);
}

// f32 -> bf16 round-to-nearest-even
__device__ __forceinline__ short f2bf(float f) {
  union { float f; unsigned u; } x; x.f = f;
  unsigned r = x.u + 0x7fffu + ((x.u >> 16) & 1u);
  return (short)(r >> 16);
}
// pack two f32 -> two bf16 (truncation) in ONE v_perm_b32
__device__ __forceinline__ unsigned pk2bf(float lo, float hi) {
  union { float f; unsigned u; } a, b; a.f = lo; b.f = hi;
  return __builtin_amdgcn_perm(b.u, a.u, 0x07060302u);
}

// ---------------------------------------------------------------------------
// Kernel 1: fused 5-way projection GEMM.  Y_p = X_p @ W_p^T (bf16 out)
// p==2 (V) writes TRANSPOSED per-head: Vt[(b*8+h)*32+d][t]  (packed b64 stores)
// ---------------------------------------------------------------------------
__global__ __launch_bounds__(256)
void proj_kernel(const float* __restrict__ content, const float* __restrict__ category,
                 const float* __restrict__ Wqc, const float* __restrict__ Wkc,
                 const float* __restrict__ Wv, const float* __restrict__ Wqk,
                 const float* __restrict__ Wkk, short* __restrict__ ws) {
  __shared__ short Al[128][40];
  __shared__ short Bl[128][40];

  const int mt = blockIdx.x;            // 0..63
  const int nt = blockIdx.y;            // 0..9
  const int p  = nt >> 1;               // projection index
  const int n0 = (nt & 1) << 7;

  const float* X = (p < 3) ? content : category;
  const float* W = (p == 0) ? Wqc : (p == 1) ? Wkc : (p == 2) ? Wv : (p == 3) ? Wqk : Wkk;
  short* Y = ws + (size_t)p * ((size_t)Mm * Dd);

  const int tid  = threadIdx.x;
  const int lane = tid & 63;
  const int wv   = tid >> 6;
  const int wm   = (wv >> 1) << 6;
  const int wn   = (wv & 1) << 6;
  const int l15  = lane & 15;
  const int l4   = lane >> 4;

  const f32x4 zero = {0.f, 0.f, 0.f, 0.f};
  f32x4 acc[4][4];
#pragma unroll
  for (int i = 0; i < 4; i++)
#pragma unroll
    for (int j = 0; j < 4; j++) acc[i][j] = zero;

  const int rs = tid >> 3;
  const int cs = (tid & 7) << 2;

  for (int k0 = 0; k0 < Dd; k0 += 32) {
#pragma unroll
    for (int pass = 0; pass < 4; pass++) {
      const int r = rs + (pass << 5);
      const float4 va = *reinterpret_cast<const float4*>(&X[(size_t)(mt * 128 + r) * Dd + k0 + cs]);
      short4v sa; sa[0] = f2bf(va.x); sa[1] = f2bf(va.y); sa[2] = f2bf(va.z); sa[3] = f2bf(va.w);
      *reinterpret_cast<short4v*>(&Al[r][cs]) = sa;
      const float4 vb = *reinterpret_cast<const float4*>(&W[(size_t)(n0 + r) * Dd + k0 + cs]);
      short4v sb; sb[0] = f2bf(vb.x); sb[1] = f2bf(vb.y); sb[2] = f2bf(vb.z); sb[3] = f2bf(vb.w);
      *reinterpret_cast<short4v*>(&Bl[r][cs]) = sb;
    }
    __syncthreads();

    short8v af[4], bfr[4];
#pragma unroll
    for (int i = 0; i < 4; i++)
      af[i] = *reinterpret_cast<const short8v*>(&Al[wm + i * 16 + l15][l4 * 8]);
#pragma unroll
    for (int j = 0; j < 4; j++)
      bfr[j] = *reinterpret_cast<const short8v*>(&Bl[wn + j * 16 + l15][l4 * 8]);
#pragma unroll
    for (int i = 0; i < 4; i++)
#pragma unroll
      for (int j = 0; j < 4; j++)
        acc[i][j] = MFMA16(af[i], bfr[j], acc[i][j]);
    __syncthreads();
  }

  if (p == 2) {
    // transposed V: Vt[(b*8+h)*32+d][t], pack 4 consecutive tokens (e) per b64
#pragma unroll
    for (int i = 0; i < 4; i++) {
      const int trow = mt * 128 + wm + i * 16 + (l4 << 2);  // token base (4-aligned)
      const int bidx = trow >> 11;
      const int tloc = trow & 2047;
#pragma unroll
      for (int j = 0; j < 4; j++) {
        const int cg = n0 + wn + j * 16 + l15;
        const int hh = cg >> 5, dd2 = cg & 31;
        short4v pk;
#pragma unroll
        for (int e = 0; e < 4; e++) pk[e] = f2bf(acc[i][j][e]);
        *reinterpret_cast<short4v*>(&Y[((size_t)(bidx * 8 + hh) * 32 + dd2) * Tt + tloc]) = pk;
      }
    }
  } else {
#pragma unroll
    for (int i = 0; i < 4; i++) {
      const int rb = mt * 128 + wm + i * 16 + (l4 << 2);
#pragma unroll
      for (int j = 0; j < 4; j++) {
        const int c = n0 + wn + j * 16 + l15;
#pragma unroll
        for (int e = 0; e < 4; e++)
          Y[(size_t)(rb + e) * Dd + c] = f2bf(acc[i][j][e]);
      }
    }
  }
}

// ---------------------------------------------------------------------------
// Kernel 2: dual causal flash attention, swapped-QK^T in-register softmax.
// Grid 512 = 32 bh (fastest, XCD locality) x 16 pairs; block handles q-tiles
// {pair, 31-pair} -> exactly 33 K-tiles of work per block (perfect balance).
// 4 waves, wave wv owns q rows wv*16..+15 (q = l15). Staging: 3x
// global_load_lds (16B) with pre-swizzled global source; K/V double-buffered.
// ---------------------------------------------------------------------------
__global__ __launch_bounds__(256, 2)
void attn_kernel(const short* __restrict__ Qc, const short* __restrict__ Kc,
                 const short* __restrict__ Vt, const short* __restrict__ Qk,
                 const short* __restrict__ Kk, short* __restrict__ AO,
                 const float* __restrict__ alpha_p) {
  __shared__ short Kcl[2][64][32];      // linear, source pre-swizzled: chunk ^= ((row>>1)&3)
  __shared__ short Kkl[2][64][32];
  __shared__ short Vtl[2][32][64];      // linear, source pre-swizzled: chunk ^= (row&7)
  __shared__ short Pl[4][2][16][64];    // per-wave/stream P, chunk ^= (q&7)

  const int bid = blockIdx.x;
  const int bh = bid & 31;
  const int pr = bid >> 5;              // 0..15
  const int b = bh >> 3, h = bh & 7;
  const size_t rowbase = (size_t)b * Tt;
  const size_t vtbase = (size_t)bh * 32 * Tt;

  const int tid = threadIdx.x, lane = tid & 63, wv = tid >> 6;
  const int l15 = lane & 15, g = lane >> 4;

  // staging source indices (pre-swizzled global chunks)
  const int krow = tid >> 2;                       // 0..63
  const int kcg  = (tid & 3) ^ ((krow >> 1) & 3);
  const int vrow = tid >> 3;                       // 0..31
  const int vcg  = (tid & 7) ^ (vrow & 7);

  const float alpha = 1.f / (1.f + __expf(-alpha_p[0]));
  const float c1 = 0.17677669529663689f * 1.4426950408889634f;  // scale*log2e
  const f32x4 zf = {0.f, 0.f, 0.f, 0.f};

  auto stage = [&](int bf, int jt2) {
    const int k0s = jt2 << 6;
    gload16(&Kc[(rowbase + k0s + krow) * Dd + h * 32 + kcg * 8],
            (char*)&Kcl[bf][0][0] + wv * 1024);
    gload16(&Kk[(rowbase + k0s + krow) * Dd + h * 32 + kcg * 8],
            (char*)&Kkl[bf][0][0] + wv * 1024);
    gload16(&Vt[vtbase + (size_t)vrow * Tt + k0s + vcg * 8],
            (char*)&Vtl[bf][0][0] + wv * 1024);
  };

  for (int ph = 0; ph < 2; ph++) {
    const int qt = ph ? (31 - pr) : pr;
    const int q0 = qt << 6;
    // Q fragments (B operand: row=q=l15, k=d=g*8+j)
    const size_t qoff = (rowbase + q0 + wv * 16 + l15) * (size_t)Dd + h * 32 + g * 8;
    const short8v qfc = *(const short8v*)&Qc[qoff];
    const short8v qfk = *(const short8v*)&Qk[qoff];

    float mx[2] = {-1e30f, -1e30f}, ls[2] = {0.f, 0.f};
    f32x4 ov[2][2];
#pragma unroll
    for (int s = 0; s < 2; s++) { ov[s][0] = zf; ov[s][1] = zf; }

    stage(0, 0);
    __syncthreads();

    for (int jt = 0; jt <= qt; jt++) {
      const int cur = jt & 1;
      if (jt < qt) stage(cur ^ 1, jt + 1);  // async prefetch into other buffer
      const bool diag = (jt == qt);
      const int nf = diag ? (wv + 1) : 4;          // frags with any unmasked kv
      const int nh2 = diag ? ((wv >> 1) + 1) : 2;  // PV kv-halves needed

      // ---- per stream: QK^T (swapped), softmax, pack, P write ----
#pragma unroll
      for (int s = 0; s < 2; s++) {
        const short (*Kl)[32] = s ? Kkl[cur] : Kcl[cur];
        const short8v qf = s ? qfk : qfc;
        f32x4 sf[4];
#pragma unroll
        for (int f = 0; f < 4; f++) {
          if (f < nf) {
            const int kr = f * 16 + l15;
            const int kc = g ^ ((kr >> 1) & 3);
            const short8v kb = *(const short8v*)&Kl[kr][kc * 8];
            sf[f] = MFMA16(kb, qf, zf);            // D[kv][q]: kv=f*16+4g+e, q=l15
            if (diag && f == wv) {
#pragma unroll
              for (int e = 0; e < 4; e++)
                if (4 * g + e > l15) sf[f][e] = -1e30f;
            }
          } else {
            sf[f] = (f32x4){-1e30f, -1e30f, -1e30f, -1e30f};
          }
        }
        // row max (lane-local 16 values + 2 shuffles)
        float pm = fmaxf(fmaxf(sf[0][0], sf[0][1]), fmaxf(sf[0][2], sf[0][3]));
#pragma unroll
        for (int f = 1; f < 4; f++)
          pm = fmaxf(pm, fmaxf(fmaxf(sf[f][0], sf[f][1]), fmaxf(sf[f][2], sf[f][3])));
        pm = fmaxf(pm, __shfl_xor(pm, 16));
        pm = fmaxf(pm, __shfl_xor(pm, 32));
        // defer-max: only rescale when max grew beyond threshold (8/c1)
        if (!__all(pm <= mx[s] + 31.36f)) {
          const float mn = fmaxf(mx[s], pm);
          const float fac = __builtin_amdgcn_exp2f((mx[s] - mn) * c1);
          mx[s] = mn;
          ls[s] *= fac;
#pragma unroll
          for (int e = 0; e < 4; e++) {            // broadcast fac to q=4g+e rows
            const float fe = __shfl(fac, ((lane >> 4) << 2) + e);
            ov[s][0][e] *= fe;
            ov[s][1][e] *= fe;
          }
        }
        const float mc = mx[s] * c1;
        float ts = 0.f;
#pragma unroll
        for (int f = 0; f < 4; f++)
#pragma unroll
          for (int e = 0; e < 4; e++) {
            const float ex = __builtin_amdgcn_exp2f(sf[f][e] * c1 - mc);
            sf[f][e] = ex;
            ts += ex;
          }
        ts += __shfl_xor(ts, 16);
        ts += __shfl_xor(ts, 32);
        ls[s] += ts;
        // pack 16 P values (block (q=l15, g): position f*4+e) -> 2 x b128
        unsigned w0 = pk2bf(sf[0][0], sf[0][1]), w1 = pk2bf(sf[0][2], sf[0][3]);
        unsigned w2 = pk2bf(sf[1][0], sf[1][1]), w3 = pk2bf(sf[1][2], sf[1][3]);
        unsigned w4 = pk2bf(sf[2][0], sf[2][1]), w5 = pk2bf(sf[2][2], sf[2][3]);
        unsigned w6 = pk2bf(sf[3][0], sf[3][1]), w7 = pk2bf(sf[3][2], sf[3][3]);
        char* Pb = (char*)&Pl[wv][s][0][0];
        const int ch0 = (g * 2 + 0) ^ (l15 & 7);
        const int ch1 = (g * 2 + 1) ^ (l15 & 7);
        *(uint4v*)(Pb + l15 * 128 + ch0 * 16) = (uint4v){w0, w1, w2, w3};
        *(uint4v*)(Pb + l15 * 128 + ch1 * 16) = (uint4v){w4, w5, w6, w7};
      }

      // ---- PV: shared V fragments, both streams ----
#pragma unroll
      for (int h2 = 0; h2 < 2; h2++) {
        if (h2 < nh2) {
          short8v vb[2];
#pragma unroll
          for (int n = 0; n < 2; n++) {
            const int vr = n * 16 + l15;
            const int vc = (h2 * 4 + g) ^ (vr & 7);
            vb[n] = *(const short8v*)&Vtl[cur][vr][vc * 8];
          }
#pragma unroll
          for (int s = 0; s < 2; s++) {
            const char* Pb = (const char*)&Pl[wv][s][0][0];
            const int fof = h2 * 2 + (g >> 1);         // source frag index
            const int gb = (g & 1) * 2;                // storage g-block
            const int inn = (fof & 1) * 8;
            const int c0 = ((gb + 0) * 2 + (fof >> 1)) ^ (l15 & 7);
            const int c1i = ((gb + 1) * 2 + (fof >> 1)) ^ (l15 & 7);
            const short4v lo = *(const short4v*)(Pb + l15 * 128 + c0 * 16 + inn);
            const short4v hi = *(const short4v*)(Pb + l15 * 128 + c1i * 16 + inn);
            short8v pa;
#pragma unroll
            for (int k = 0; k < 4; k++) { pa[k] = lo[k]; pa[4 + k] = hi[k]; }
            __builtin_amdgcn_s_setprio(1);
#pragma unroll
            for (int n = 0; n < 2; n++) ov[s][n] = MFMA16(pa, vb[n], ov[s][n]);
            __builtin_amdgcn_s_setprio(0);
          }
        }
      }
      __syncthreads();  // prefetch landed + all reads of cur done
    }

    // ---- combine streams, normalize, store ----
    float r0[4], r1[4];
#pragma unroll
    for (int e = 0; e < 4; e++) {
      const float l0 = __shfl(ls[0], ((lane >> 4) << 2) + e);
      const float l1 = __shfl(ls[1], ((lane >> 4) << 2) + e);
      r0[e] = (1.f - alpha) / l0;
      r1[e] = alpha / l1;
    }
    const size_t orow = rowbase + q0 + wv * 16 + g * 4;
#pragma unroll
    for (int n = 0; n < 2; n++)
#pragma unroll
      for (int e = 0; e < 4; e++) {
        const float o = ov[0][n][e] * r0[e] + ov[1][n][e] * r1[e];
        AO[(orow + e) * Dd + h * 32 + n * 16 + l15] = f2bf(o);
      }
  }
}

// ---------------------------------------------------------------------------
// Kernel 3: output projection  out = AO @ Wo^T + bo  (f32 out)
// ---------------------------------------------------------------------------
__global__ __launch_bounds__(256)
void outproj_kernel(const short* __restrict__ AO, const float* __restrict__ Wo,
                    const float* __restrict__ bo, float* __restrict__ out) {
  __shared__ short Al[128][40];
  __shared__ short Bl[128][40];

  const int mt = blockIdx.x;
  const int n0 = (int)blockIdx.y << 7;

  const int tid  = threadIdx.x;
  const int lane = tid & 63;
  const int wv   = tid >> 6;
  const int wm   = (wv >> 1) << 6;
  const int wn   = (wv & 1) << 6;
  const int l15  = lane & 15;
  const int l4   = lane >> 4;

  const f32x4 zero = {0.f, 0.f, 0.f, 0.f};
  f32x4 acc[4][4];
#pragma unroll
  for (int i = 0; i < 4; i++)
#pragma unroll
    for (int j = 0; j < 4; j++) acc[i][j] = zero;

  const int rs2 = tid >> 2;
  const int sg2 = tid & 3;
  const int rs  = tid >> 3;
  const int cs  = (tid & 7) << 2;

  for (int k0 = 0; k0 < Dd; k0 += 32) {
#pragma unroll
    for (int pass = 0; pass < 2; pass++) {
      const int r = rs2 + (pass << 6);
      *reinterpret_cast<short8v*>(&Al[r][sg2 * 8]) =
          *reinterpret_cast<const short8v*>(&AO[(size_t)(mt * 128 + r) * Dd + k0 + sg2 * 8]);
    }
#pragma unroll
    for (int pass = 0; pass < 4; pass++) {
      const int r = rs + (pass << 5);
      const float4 vb = *reinterpret_cast<const float4*>(&Wo[(size_t)(n0 + r) * Dd + k0 + cs]);
      short4v sb; sb[0] = f2bf(vb.x); sb[1] = f2bf(vb.y); sb[2] = f2bf(vb.z); sb[3] = f2bf(vb.w);
      *reinterpret_cast<short4v*>(&Bl[r][cs]) = sb;
    }
    __syncthreads();

    short8v af[4], bfr[4];
#pragma unroll
    for (int i = 0; i < 4; i++)
      af[i] = *reinterpret_cast<const short8v*>(&Al[wm + i * 16 + l15][l4 * 8]);
#pragma unroll
    for (int j = 0; j < 4; j++)
      bfr[j] = *reinterpret_cast<const short8v*>(&Bl[wn + j * 16 + l15][l4 * 8]);
#pragma unroll
    for (int i = 0; i < 4; i++)
#pragma unroll
      for (int j = 0; j < 4; j++)
        acc[i][j] = MFMA16(af[i], bfr[j], acc[i][j]);
    __syncthreads();
  }

#pragma unroll
  for (int i = 0; i < 4; i++) {
    const int rb = mt * 128 + wm + i * 16 + (l4 << 2);
#pragma unroll
    for (int j = 0; j < 4; j++) {
      const int c = n0 + wn + j * 16 + l15;
      const float bias = bo[c];
#pragma unroll
      for (int e = 0; e < 4; e++)
        out[(size_t)(rb + e) * Dd + c] = acc[i][j][e] + bias;
    }
  }
}

// ---------------------------------------------------------------------------
extern "C" void kernel_launch(void* const* d_in, const int* in_sizes, int n_in,
                              void* d_out, int out_size, void* d_ws, size_t ws_size,
                              hipStream_t stream) {
  const float* content = (const float*)d_in[0];
  const float* category = (const float*)d_in[1];
  const float* Wqc = (const float*)d_in[2];
  const float* Wkc = (const float*)d_in[3];
  const float* Wv  = (const float*)d_in[4];
  const float* Wqk = (const float*)d_in[5];
  const float* Wkk = (const float*)d_in[6];
  const float* Wo  = (const float*)d_in[7];
  const float* bo  = (const float*)d_in[8];
  const float* alpha_logit = (const float*)d_in[9];
  float* out = (float*)d_out;

  short* ws = (short*)d_ws;
  const size_t buf = (size_t)Mm * Dd;   // 2M bf16 = 4MB per buffer
  short* Qc = ws + 0 * buf;
  short* Kc = ws + 1 * buf;
  short* Vt = ws + 2 * buf;             // transposed: [(b*8+h)*32+d][t]
  short* Qk = ws + 3 * buf;
  short* Kk = ws + 4 * buf;
  short* AO = ws + 5 * buf;             // 24MB of d_ws total

  proj_kernel<<<dim3(64, 10), 256, 0, stream>>>(content, category, Wqc, Wkc, Wv, Wqk, Wkk, ws);
  attn_kernel<<<dim3(512), 256, 0, stream>>>(Qc, Kc, Vt, Qk, Kk, AO, alpha_logit);
  outproj_kernel<<<dim3(64, 2), 256, 0, stream>>>(AO, Wo, bo, out);
}